// Round 9
// baseline (391.744 us; speedup 1.0000x reference)
//
#include <hip/hip_runtime.h>
#include <cstddef>
#include <cstdint>

#define CH 128       // IN_CH == HID_CH == 128
#define NBKT 196     // dst >> 9 -> buckets 0..195 (512 nodes each)
#define ABLK 1280    // binning blocks (chunk = 1250) — R8's ordered write-out makes this safe
#define BKT_NODES 512
#define BKTCAP 10240 // fixed per-bucket region (mean 8192, sigma ~90 -> +22 sigma)
#define LCHUNK 1280  // LDS staging capacity (>= chunk = 1250)

typedef __attribute__((ext_vector_type(8))) short short8;
typedef __attribute__((ext_vector_type(4))) float f32x4;

__device__ __forceinline__ unsigned short f2bf(float f) {
  unsigned u = __float_as_uint(f);
  u += 0x7FFF + ((u >> 16) & 1);   // round-to-nearest-even
  return (unsigned short)(u >> 16);
}
__device__ __forceinline__ float bf_lo(unsigned int u) {   // low bf16 of packed pair
  return __uint_as_float(u << 16);
}
__device__ __forceinline__ float bf_hi(unsigned int u) {   // high bf16 of packed pair
  return __uint_as_float(u & 0xffff0000u);
}
__device__ __forceinline__ void gld16(const void* g, void* l) {
  __builtin_amdgcn_global_load_lds((const __attribute__((address_space(1))) unsigned int*)g,
                                   (__attribute__((address_space(3))) unsigned int*)l, 16, 0, 0);
}

// ====================== fused preamble+binning: bin | wt | cvt (independent block ranges) =======
// Binning branch: block-local counting sort (hist -> scan -> global ticket -> LDS scatter ->
// ordered write-out). R8 proved the ordered write-out kills write amplification (59->33 MB);
// R7/R8 proved the remaining cost is per-block serial-chain latency at only 320 blocks.
// Now: 4x blocks (1280, chunk 1250) with the ordered write-out kept. LDS ~10 KB.
__global__ void k_prebin(const int* __restrict__ src, const int* __restrict__ dst,
                         int* __restrict__ cnt, unsigned int* __restrict__ binned,
                         int E, int chunk,
                         const float4* __restrict__ in, uint4* __restrict__ out, int n8,
                         const float* __restrict__ w0, const float* __restrict__ w1,
                         const float* __restrict__ w2, const float* __restrict__ w3,
                         const float* __restrict__ w4, unsigned short* __restrict__ wdst) {
  __shared__ int c[NBKT];
  __shared__ int gb[NBKT];        // gbase - lbase per bucket
  __shared__ int lcur[NBKT];      // local scatter cursor (starts at lbase)
  __shared__ int sc[256];
  __shared__ unsigned rec[LCHUNK];
  __shared__ unsigned char rb[LCHUNK];
  int b = blockIdx.x;
  int t = threadIdx.x;
  if (b < ABLK) {
    for (int i = t; i < NBKT; i += 256) c[i] = 0;
    __syncthreads();
    int s = b * chunk;
    int e = min(s + chunk, E);
    int n = e - s;
    for (int i = s + t; i < e; i += 256)
      atomicAdd(&c[dst[i] >> 9], 1);
    __syncthreads();
    // inclusive scan over bucket counts (padded to 256)
    int cv = (t < NBKT) ? c[t] : 0;
    sc[t] = cv;
    __syncthreads();
    for (int o = 1; o < 256; o <<= 1) {
      int y = (t >= o) ? sc[t - o] : 0;
      __syncthreads();
      sc[t] += y;
      __syncthreads();
    }
    if (t < NBKT) {
      int lb = sc[t] - cv;                      // local base
      lcur[t] = lb;
      gb[t] = atomicAdd(&cnt[t], cv) - lb;      // global ticket base minus local base
    }
    __syncthreads();
    // bucket-ordered scatter into LDS
    for (int i = s + t; i < e; i += 256) {
      int d = dst[i];
      int bb = d >> 9;
      int lp = atomicAdd(&lcur[bb], 1);
      rec[lp] = (unsigned)src[i] | ((unsigned)(d & 511) << 17);
      rb[lp] = (unsigned char)bb;
    }
    __syncthreads();
    // ordered, near-coalesced write-out
    for (int i = t; i < n; i += 256) {
      int bb = rb[i];
      binned[(size_t)bb * BKTCAP + gb[bb] + i] = rec[i];
    }
  } else if (b < ABLK + 5) {
    const float* srcs[5] = {w0, w1, w2, w3, w4};
    const float* w = srcs[b - ABLK];
    unsigned short* d = wdst + (size_t)(b - ABLK) * CH * CH;
    for (int idx = t; idx < CH * CH; idx += 256) {
      int k = idx >> 7, nn = idx & 127;
      d[nn * CH + k] = f2bf(w[idx]);
    }
  } else {
    int i = (b - ABLK - 5) * 256 + t;
    if (i < n8) {
      float4 a = in[i * 2], cc = in[i * 2 + 1];
      uint4 o;
      o.x = (unsigned)f2bf(a.x) | ((unsigned)f2bf(a.y) << 16);
      o.y = (unsigned)f2bf(a.z) | ((unsigned)f2bf(a.w) << 16);
      o.z = (unsigned)f2bf(cc.x) | ((unsigned)f2bf(cc.y) << 16);
      o.w = (unsigned)f2bf(cc.z) | ((unsigned)f2bf(cc.w) << 16);
      out[i] = o;
    }
  }
}

// ============================ bucket pass: per-bucket hist + scan + rowptr + scatter ============
__global__ __launch_bounds__(256)
void k_bucket(const unsigned int* __restrict__ binned, const int* __restrict__ cnt,
              int* __restrict__ rowptr, int* __restrict__ sorted, int N, int E, int nbkt) {
  __shared__ int c[BKT_NODES];
  __shared__ int tsum[256];
  __shared__ int cur[BKT_NODES];
  __shared__ int bscan[256];
  int b = blockIdx.x, t = threadIdx.x;
  // block-wide inclusive scan over bucket counts
  int cv = (t < nbkt) ? cnt[t] : 0;
  bscan[t] = cv;
  __syncthreads();
  for (int o = 1; o < 256; o <<= 1) {
    int y = (t >= o) ? bscan[t - o] : 0;
    __syncthreads();
    bscan[t] += y;
    __syncthreads();
  }
  int cntb = cnt[b];
  int gbase = bscan[b] - cntb;            // global edge offset of this bucket
  size_t sread = (size_t)b * BKTCAP;      // fixed read region

  c[t] = 0; c[t + 256] = 0;
  __syncthreads();
  for (int i = t; i < cntb; i += 256)
    atomicAdd(&c[binned[sread + i] >> 17], 1);
  __syncthreads();
  int v0 = c[2 * t], v1 = c[2 * t + 1];
  int tot = v0 + v1;
  tsum[t] = tot;
  __syncthreads();
  for (int o = 1; o < 256; o <<= 1) {
    int y = (t >= o) ? tsum[t - o] : 0;
    __syncthreads();
    tsum[t] += y;
    __syncthreads();
  }
  int excl = tsum[t] - tot;
  int base = b * BKT_NODES;
  int r0 = gbase + excl, r1 = gbase + excl + v0;
  if (base + 2 * t < N)     rowptr[base + 2 * t]     = r0;
  if (base + 2 * t + 1 < N) rowptr[base + 2 * t + 1] = r1;
  cur[2 * t] = r0; cur[2 * t + 1] = r1;
  __syncthreads();
  for (int i = t; i < cntb; i += 256) {
    unsigned w = binned[sread + i];
    int pos = atomicAdd(&cur[w >> 17], 1);   // LDS atomic
    sorted[pos] = w & 0x1FFFF;
  }
  if (b == nbkt - 1 && t == 0) rowptr[N] = E;
}

// ============================ mean aggregation v5 ============================
// At the per-XCD compulsory-traffic ceiling (~178 MB fetch, ~3.5 TB/s) — done.
__global__ __launch_bounds__(256)
void k_agg(const uint4* __restrict__ in4, uint4* __restrict__ out4,
           const int* __restrict__ rowptr, const int* __restrict__ sorted_src,
           int n, int nwaves) {
  int wid = (blockIdx.x * 256 + threadIdx.x) >> 6;
  int lane = threadIdx.x & 63;
  int quad = lane >> 4;        // edge sub-slot 0..3
  int sl = lane & 15;          // uint4 index within 128-ch row (16 x 16 B = 256 B)

  for (int node = wid; node < n; node += nwaves) {
    int beg = rowptr[node], end = rowptr[node + 1];
    float a0 = 0.f, a1 = 0.f, a2 = 0.f, a3 = 0.f;
    float a4 = 0.f, a5 = 0.f, a6 = 0.f, a7 = 0.f;
    int e = beg;
    for (; e + 16 <= end; e += 16) {     // 4 quad-iterations = 16 edges
      uint4 v[4];
#pragma unroll
      for (int j = 0; j < 4; j++)
        v[j] = in4[((unsigned)sorted_src[e + 4 * j + quad] << 4) + sl];
#pragma unroll
      for (int j = 0; j < 4; j++) {
        a0 += bf_lo(v[j].x); a1 += bf_hi(v[j].x);
        a2 += bf_lo(v[j].y); a3 += bf_hi(v[j].y);
        a4 += bf_lo(v[j].z); a5 += bf_hi(v[j].z);
        a6 += bf_lo(v[j].w); a7 += bf_hi(v[j].w);
      }
    }
    if (e < end) {                        // masked tail block (value-predicated)
      uint4 v[4];
#pragma unroll
      for (int j = 0; j < 4; j++) {
        int k = e + 4 * j + quad;
        int idx = (k < end) ? k : beg;    // clamped loads hit L1 (row[beg] hot)
        uint4 tv = in4[((unsigned)sorted_src[idx] << 4) + sl];
        if (k >= end) { tv.x = 0u; tv.y = 0u; tv.z = 0u; tv.w = 0u; }
        v[j] = tv;
      }
#pragma unroll
      for (int j = 0; j < 4; j++) {
        a0 += bf_lo(v[j].x); a1 += bf_hi(v[j].x);
        a2 += bf_lo(v[j].y); a3 += bf_hi(v[j].y);
        a4 += bf_lo(v[j].z); a5 += bf_hi(v[j].z);
        a6 += bf_lo(v[j].w); a7 += bf_hi(v[j].w);
      }
    }
    a0 += __shfl(a0, lane ^ 16); a1 += __shfl(a1, lane ^ 16);
    a2 += __shfl(a2, lane ^ 16); a3 += __shfl(a3, lane ^ 16);
    a4 += __shfl(a4, lane ^ 16); a5 += __shfl(a5, lane ^ 16);
    a6 += __shfl(a6, lane ^ 16); a7 += __shfl(a7, lane ^ 16);
    a0 += __shfl(a0, lane ^ 32); a1 += __shfl(a1, lane ^ 32);
    a2 += __shfl(a2, lane ^ 32); a3 += __shfl(a3, lane ^ 32);
    a4 += __shfl(a4, lane ^ 32); a5 += __shfl(a5, lane ^ 32);
    a6 += __shfl(a6, lane ^ 32); a7 += __shfl(a7, lane ^ 32);
    int d = end - beg;
    float inv = (d > 0) ? (1.f / (float)d) : 0.f;
    if (quad == 0) {
      uint4 o;
      o.x = (unsigned)f2bf(a0 * inv) | ((unsigned)f2bf(a1 * inv) << 16);
      o.y = (unsigned)f2bf(a2 * inv) | ((unsigned)f2bf(a3 * inv) << 16);
      o.z = (unsigned)f2bf(a4 * inv) | ((unsigned)f2bf(a5 * inv) << 16);
      o.w = (unsigned)f2bf(a6 * inv) | ((unsigned)f2bf(a7 * inv) << 16);
      out4[((unsigned)node << 4) + sl] = o;
    }
  }
}

// ============================ fused SAGE dual-GEMM via MFMA bf16 (R2-proven form) ===============
__global__ __launch_bounds__(256, 2)
void k_sage(const unsigned short* __restrict__ Am, const unsigned short* __restrict__ Ax,
            const unsigned short* __restrict__ WTl, const unsigned short* __restrict__ WTr,
            const float* __restrict__ bias, unsigned short* __restrict__ out, int n) {
  __shared__ unsigned short sA[128 * 64];
  __shared__ unsigned short sB[128 * 64];
  int tid = threadIdx.x;
  int lane = tid & 63;
  int w = tid >> 6;
  int row0 = blockIdx.x * 128;
  int col_lo = lane & 15, quad = lane >> 4;
  int rx = col_lo & 7;            // row&7 of every fragment row this lane reads

  f32x4 acc[2][8];
#pragma unroll
  for (int mt = 0; mt < 2; mt++)
#pragma unroll
    for (int nt = 0; nt < 8; nt++) acc[mt][nt] = (f32x4){0.f, 0.f, 0.f, 0.f};

  const unsigned short* As[4] = {Am, Am, Ax, Ax};
  const unsigned short* Bs[4] = {WTl, WTl, WTr, WTr};
  const int k0s[4] = {0, 64, 0, 64};

  for (int c = 0; c < 4; c++) {
    const unsigned short* Ap = As[c];
    const unsigned short* Bp = Bs[c];
    int k0 = k0s[c];
#pragma unroll
    for (int it = 0; it < 4; it++) {
      int flat = it * 256 + tid;
      int r = flat >> 3;
      int sl8 = flat & 7;
      int kof = (sl8 ^ (r & 7)) * 8;     // inverse-swizzled global slot
      int gr = row0 + r;
      if (gr > n - 1) gr = n - 1;
      gld16(Ap + (size_t)gr * CH + k0 + kof, sA + flat * 8);
      gld16(Bp + (size_t)r * CH + k0 + kof, sB + flat * 8);
    }
    __syncthreads();

#pragma unroll
    for (int ks = 0; ks < 2; ks++) {
      int so = ((ks * 4 + quad) ^ rx) * 8;   // swizzled slot offset (shorts)
      short8 a0 = *(const short8*)&sA[(w * 32 + col_lo) * 64 + so];
      short8 a1 = *(const short8*)&sA[(w * 32 + 16 + col_lo) * 64 + so];
      short8 b[8];
#pragma unroll
      for (int nt = 0; nt < 8; nt++)
        b[nt] = *(const short8*)&sB[(nt * 16 + col_lo) * 64 + so];
#pragma unroll
      for (int nt = 0; nt < 8; nt++) {
        acc[0][nt] = __builtin_amdgcn_mfma_f32_16x16x32_bf16(a0, b[nt], acc[0][nt], 0, 0, 0);
        acc[1][nt] = __builtin_amdgcn_mfma_f32_16x16x32_bf16(a1, b[nt], acc[1][nt], 0, 0, 0);
      }
    }
    __syncthreads();
  }

#pragma unroll
  for (int nt = 0; nt < 8; nt++) {
    float bb = bias[nt * 16 + col_lo];
#pragma unroll
    for (int mt = 0; mt < 2; mt++) {
#pragma unroll
      for (int r = 0; r < 4; r++) {
        int rr = row0 + w * 32 + mt * 16 + quad * 4 + r;
        if (rr < n) {
          float v = fmaxf(acc[mt][nt][r] + bb, 0.f);
          out[(size_t)rr * CH + nt * 16 + col_lo] = f2bf(v);
        }
      }
    }
  }
}

// ============================ decoder GEMM via MFMA (R2-proven form) ============================
__global__ __launch_bounds__(256, 2)
void k_dec(const unsigned short* __restrict__ H, const unsigned short* __restrict__ WTd,
           const float* __restrict__ bd, const float* __restrict__ X,
           const float* __restrict__ alpha_p, float* __restrict__ out, int n) {
  __shared__ unsigned short sA[128 * 64];
  __shared__ unsigned short sB[128 * 64];
  int tid = threadIdx.x;
  int lane = tid & 63;
  int w = tid >> 6;
  int row0 = blockIdx.x * 128;
  int col_lo = lane & 15, quad = lane >> 4;
  int rx = col_lo & 7;

  f32x4 acc[2][8];
#pragma unroll
  for (int mt = 0; mt < 2; mt++)
#pragma unroll
    for (int nt = 0; nt < 8; nt++) acc[mt][nt] = (f32x4){0.f, 0.f, 0.f, 0.f};

  for (int c = 0; c < 2; c++) {
    int k0 = c * 64;
#pragma unroll
    for (int it = 0; it < 4; it++) {
      int flat = it * 256 + tid;
      int r = flat >> 3;
      int sl8 = flat & 7;
      int kof = (sl8 ^ (r & 7)) * 8;
      int gr = row0 + r;
      if (gr > n - 1) gr = n - 1;
      gld16(H + (size_t)gr * CH + k0 + kof, sA + flat * 8);
      gld16(WTd + (size_t)r * CH + k0 + kof, sB + flat * 8);
    }
    __syncthreads();

#pragma unroll
    for (int ks = 0; ks < 2; ks++) {
      int so = ((ks * 4 + quad) ^ rx) * 8;
      short8 a0 = *(const short8*)&sA[(w * 32 + col_lo) * 64 + so];
      short8 a1 = *(const short8*)&sA[(w * 32 + 16 + col_lo) * 64 + so];
      short8 b[8];
#pragma unroll
      for (int nt = 0; nt < 8; nt++)
        b[nt] = *(const short8*)&sB[(nt * 16 + col_lo) * 64 + so];
#pragma unroll
      for (int nt = 0; nt < 8; nt++) {
        acc[0][nt] = __builtin_amdgcn_mfma_f32_16x16x32_bf16(a0, b[nt], acc[0][nt], 0, 0, 0);
        acc[1][nt] = __builtin_amdgcn_mfma_f32_16x16x32_bf16(a1, b[nt], acc[1][nt], 0, 0, 0);
      }
    }
    __syncthreads();
  }

  float al = alpha_p[0];
  float be = 1.f - al;
#pragma unroll
  for (int nt = 0; nt < 8; nt++) {
    float bb = bd[nt * 16 + col_lo];
#pragma unroll
    for (int mt = 0; mt < 2; mt++) {
#pragma unroll
      for (int r = 0; r < 4; r++) {
        int rr = row0 + w * 32 + mt * 16 + quad * 4 + r;
        if (rr < n) {
          int cc = nt * 16 + col_lo;
          float xv = X[(size_t)rr * CH + cc];
          out[(size_t)rr * CH + cc] = al * (acc[mt][nt][r] + bb) + be * xv;
        }
      }
    }
  }
}

// ============================ launch ============================

extern "C" void kernel_launch(void* const* d_in, const int* in_sizes, int n_in,
                              void* d_out, int out_size, void* d_ws, size_t ws_size,
                              hipStream_t stream) {
  const float* x   = (const float*)d_in[0];
  const int*   ei  = (const int*)d_in[1];
  const float* W1l = (const float*)d_in[2];
  const float* b1  = (const float*)d_in[3];
  const float* W1r = (const float*)d_in[4];
  const float* W2l = (const float*)d_in[5];
  const float* b2  = (const float*)d_in[6];
  const float* W2r = (const float*)d_in[7];
  const float* Wd  = (const float*)d_in[8];
  const float* bd  = (const float*)d_in[9];
  const float* alp = (const float*)d_in[10];

  int N = in_sizes[0] / CH;   // 100000
  int E = in_sizes[1] / 2;    // 1600000
  const int* src = ei;
  const int* dst = ei + E;

  char* ws = (char*)d_ws;
  size_t off = 0;
  auto alloc = [&](size_t bytes) -> char* {
    off = (off + 511) & ~size_t(511);
    char* p = ws + off;
    off += bytes;
    return p;
  };
  int*   rowptr = (int*)alloc((size_t)(N + 1) * 4);
  int*   cnt    = (int*)alloc((size_t)NBKT * 4);
  int*   sorted = (int*)alloc((size_t)E * 4);
  unsigned short* xb = (unsigned short*)alloc((size_t)N * CH * 2);
  unsigned short* h  = (unsigned short*)alloc((size_t)N * CH * 2);
  unsigned short* WT = (unsigned short*)alloc((size_t)5 * CH * CH * 2);
  unsigned short* mean = (unsigned short*)d_out;
  unsigned int* binned = (unsigned int*)((char*)d_out + (size_t)N * CH * 2);  // 8.03 MB fixed regions

  int chunk = (E + ABLK - 1) / ABLK;   // 1250
  int n8 = N * CH / 8;                 // 1,600,000
  int gCvt = (n8 + 255) / 256;         // 6250

  // 0) zero bucket counters (graph-capture-safe async memset)
  hipMemsetAsync(cnt, 0, (size_t)NBKT * 4, stream);
  // 1) fused binning + weight transpose + x convert
  k_prebin<<<ABLK + 5 + gCvt, 256, 0, stream>>>(src, dst, cnt, binned, E, chunk,
                                                (const float4*)x, (uint4*)xb, n8,
                                                W1l, W1r, W2l, W2r, Wd, WT);
  // 2) bucket pass (prefix over 196 counts + per-node sort + rowptr)
  k_bucket<<<NBKT, 256, 0, stream>>>(binned, cnt, rowptr, sorted, N, E, NBKT);

  int gAggBlocks = 6144;               // 24576 wave-slots, ~4 nodes/wave (3x oversubscribed)
  int nWaves = gAggBlocks * 4;
  int gGemm = (N + 127) / 128;
  unsigned short* WT1l = WT + 0 * CH * CH;
  unsigned short* WT1r = WT + 1 * CH * CH;
  unsigned short* WT2l = WT + 2 * CH * CH;
  unsigned short* WT2r = WT + 3 * CH * CH;
  unsigned short* WTd  = WT + 4 * CH * CH;

  k_agg<<<gAggBlocks, 256, 0, stream>>>((const uint4*)xb, (uint4*)mean, rowptr, sorted, N, nWaves);
  k_sage<<<gGemm, 256, 0, stream>>>(mean, xb, WT1l, WT1r, b1, h, N);
  k_agg<<<gAggBlocks, 256, 0, stream>>>((const uint4*)h, (uint4*)mean, rowptr, sorted, N, nWaves);
  k_sage<<<gGemm, 256, 0, stream>>>(mean, h, WT2l, WT2r, b2, h, N);
  k_dec<<<gGemm, 256, 0, stream>>>(h, WTd, bd, x, alp, (float*)d_out, N);
}

// Round 11
// 350.258 us; speedup vs baseline: 1.1184x; 1.1184x over previous
//
#include <hip/hip_runtime.h>
#include <cstddef>
#include <cstdint>

#define CH 128       // IN_CH == HID_CH == 128
#define NBKT 196     // dst >> 9 -> buckets 0..195 (512 nodes each)
#define ABLK 320     // binning blocks (chunk = 5000)
#define BKT_NODES 512
#define BKTCAP 10240 // fixed per-bucket region (mean 8192, sigma ~90 -> +22 sigma)

typedef __attribute__((ext_vector_type(8))) short short8;
typedef __attribute__((ext_vector_type(4))) float f32x4;

__device__ __forceinline__ unsigned short f2bf(float f) {
  unsigned u = __float_as_uint(f);
  u += 0x7FFF + ((u >> 16) & 1);   // round-to-nearest-even
  return (unsigned short)(u >> 16);
}
__device__ __forceinline__ float bf_lo(unsigned int u) {   // low bf16 of packed pair
  return __uint_as_float(u << 16);
}
__device__ __forceinline__ float bf_hi(unsigned int u) {   // high bf16 of packed pair
  return __uint_as_float(u & 0xffff0000u);
}
__device__ __forceinline__ void gld16(const void* g, void* l) {
  __builtin_amdgcn_global_load_lds((const __attribute__((address_space(1))) unsigned int*)g,
                                   (__attribute__((address_space(3))) unsigned int*)l, 16, 0, 0);
}

// ====================== fused preamble+binning: bin | wt | cvt (independent block ranges) =======
// R6's naive-scatter binning (WRITE_SIZE 33.9 MB — fine at 25-word runs) but at 1024
// threads/block: the 5000-edge chunk is processed in 5 serial rounds instead of 20,
// attacking the latency chain that held the binning tail at 61.5 us / 27% occupancy.
__global__ __launch_bounds__(1024)
void k_prebin(const int* __restrict__ src, const int* __restrict__ dst,
              int* __restrict__ cnt, unsigned int* __restrict__ binned,
              int E, int chunk,
              const float4* __restrict__ in, uint4* __restrict__ out, int n8,
              const float* __restrict__ w0, const float* __restrict__ w1,
              const float* __restrict__ w2, const float* __restrict__ w3,
              const float* __restrict__ w4, unsigned short* __restrict__ wdst) {
  __shared__ int c[NBKT];
  __shared__ int curq[NBKT];
  int b = blockIdx.x;
  int t = threadIdx.x;
  if (b < ABLK) {
    for (int i = t; i < NBKT; i += 1024) c[i] = 0;
    __syncthreads();
    int s = b * chunk;
    int e = min(s + chunk, E);
    for (int i = s + t; i < e; i += 1024)
      atomicAdd(&c[dst[i] >> 9], 1);
    __syncthreads();
    for (int i = t; i < NBKT; i += 1024)
      curq[i] = atomicAdd(&cnt[i], c[i]);   // global ticket: this block's base within bucket
    __syncthreads();
    for (int i = s + t; i < e; i += 1024) {
      int d = dst[i];
      int bb = d >> 9;
      int pos = atomicAdd(&curq[bb], 1);    // LDS cursor
      binned[(size_t)bb * BKTCAP + pos] = (unsigned)src[i] | ((unsigned)(d & 511) << 17);
    }
  } else if (b < ABLK + 5) {
    const float* srcs[5] = {w0, w1, w2, w3, w4};
    const float* w = srcs[b - ABLK];
    unsigned short* d = wdst + (size_t)(b - ABLK) * CH * CH;
    for (int idx = t; idx < CH * CH; idx += 1024) {
      int k = idx >> 7, nn = idx & 127;
      d[nn * CH + k] = f2bf(w[idx]);
    }
  } else {
    int i = (b - ABLK - 5) * 1024 + t;
    if (i < n8) {
      float4 a = in[i * 2], cc = in[i * 2 + 1];
      uint4 o;
      o.x = (unsigned)f2bf(a.x) | ((unsigned)f2bf(a.y) << 16);
      o.y = (unsigned)f2bf(a.z) | ((unsigned)f2bf(a.w) << 16);
      o.z = (unsigned)f2bf(cc.x) | ((unsigned)f2bf(cc.y) << 16);
      o.w = (unsigned)f2bf(cc.z) | ((unsigned)f2bf(cc.w) << 16);
      out[i] = o;
    }
  }
}

// ============================ bucket pass (1024 threads): hist + scan + rowptr + scatter ========
// Heavy loops (hist over ~8550 edges, scatter) use all 16 waves: 34 -> 9 serial rounds.
// Scans stay on t<256 (all threads execute the barriers).
__global__ __launch_bounds__(1024)
void k_bucket(const unsigned int* __restrict__ binned, const int* __restrict__ cnt,
              int* __restrict__ rowptr, int* __restrict__ sorted, int N, int E, int nbkt) {
  __shared__ int c[BKT_NODES];
  __shared__ int tsum[256];
  __shared__ int cur[BKT_NODES];
  __shared__ int bscan[256];
  int b = blockIdx.x, t = threadIdx.x;
  // inclusive scan over bucket counts (t<256 active)
  int cv = 0;
  if (t < 256) { cv = (t < nbkt) ? cnt[t] : 0; bscan[t] = cv; }
  __syncthreads();
  for (int o = 1; o < 256; o <<= 1) {
    int y = 0;
    if (t < 256 && t >= o) y = bscan[t - o];
    __syncthreads();
    if (t < 256) bscan[t] += y;
    __syncthreads();
  }
  int cntb = cnt[b];
  int gbase = bscan[b] - cntb;            // global edge offset of this bucket
  size_t sread = (size_t)b * BKTCAP;      // fixed read region

  if (t < BKT_NODES) c[t] = 0;
  __syncthreads();
  for (int i = t; i < cntb; i += 1024)
    atomicAdd(&c[binned[sread + i] >> 17], 1);
  __syncthreads();
  int v0 = 0, v1 = 0, tot = 0;
  if (t < 256) { v0 = c[2 * t]; v1 = c[2 * t + 1]; tot = v0 + v1; tsum[t] = tot; }
  __syncthreads();
  for (int o = 1; o < 256; o <<= 1) {
    int y = 0;
    if (t < 256 && t >= o) y = tsum[t - o];
    __syncthreads();
    if (t < 256) tsum[t] += y;
    __syncthreads();
  }
  if (t < 256) {
    int excl = tsum[t] - tot;
    int base = b * BKT_NODES;
    int r0 = gbase + excl, r1 = gbase + excl + v0;
    if (base + 2 * t < N)     rowptr[base + 2 * t]     = r0;
    if (base + 2 * t + 1 < N) rowptr[base + 2 * t + 1] = r1;
    cur[2 * t] = r0; cur[2 * t + 1] = r1;
  }
  __syncthreads();
  for (int i = t; i < cntb; i += 1024) {
    unsigned w = binned[sread + i];
    int pos = atomicAdd(&cur[w >> 17], 1);   // LDS atomic
    sorted[pos] = w & 0x1FFFF;
  }
  if (b == nbkt - 1 && t == 0) rowptr[N] = E;
}

// ============================ mean aggregation v5 ============================
// At the per-XCD compulsory-traffic ceiling (~178 MB fetch, ~3.5 TB/s) — done.
__global__ __launch_bounds__(256)
void k_agg(const uint4* __restrict__ in4, uint4* __restrict__ out4,
           const int* __restrict__ rowptr, const int* __restrict__ sorted_src,
           int n, int nwaves) {
  int wid = (blockIdx.x * 256 + threadIdx.x) >> 6;
  int lane = threadIdx.x & 63;
  int quad = lane >> 4;        // edge sub-slot 0..3
  int sl = lane & 15;          // uint4 index within 128-ch row (16 x 16 B = 256 B)

  for (int node = wid; node < n; node += nwaves) {
    int beg = rowptr[node], end = rowptr[node + 1];
    float a0 = 0.f, a1 = 0.f, a2 = 0.f, a3 = 0.f;
    float a4 = 0.f, a5 = 0.f, a6 = 0.f, a7 = 0.f;
    int e = beg;
    for (; e + 16 <= end; e += 16) {     // 4 quad-iterations = 16 edges
      uint4 v[4];
#pragma unroll
      for (int j = 0; j < 4; j++)
        v[j] = in4[((unsigned)sorted_src[e + 4 * j + quad] << 4) + sl];
#pragma unroll
      for (int j = 0; j < 4; j++) {
        a0 += bf_lo(v[j].x); a1 += bf_hi(v[j].x);
        a2 += bf_lo(v[j].y); a3 += bf_hi(v[j].y);
        a4 += bf_lo(v[j].z); a5 += bf_hi(v[j].z);
        a6 += bf_lo(v[j].w); a7 += bf_hi(v[j].w);
      }
    }
    if (e < end) {                        // masked tail block (value-predicated)
      uint4 v[4];
#pragma unroll
      for (int j = 0; j < 4; j++) {
        int k = e + 4 * j + quad;
        int idx = (k < end) ? k : beg;    // clamped loads hit L1 (row[beg] hot)
        uint4 tv = in4[((unsigned)sorted_src[idx] << 4) + sl];
        if (k >= end) { tv.x = 0u; tv.y = 0u; tv.z = 0u; tv.w = 0u; }
        v[j] = tv;
      }
#pragma unroll
      for (int j = 0; j < 4; j++) {
        a0 += bf_lo(v[j].x); a1 += bf_hi(v[j].x);
        a2 += bf_lo(v[j].y); a3 += bf_hi(v[j].y);
        a4 += bf_lo(v[j].z); a5 += bf_hi(v[j].z);
        a6 += bf_lo(v[j].w); a7 += bf_hi(v[j].w);
      }
    }
    a0 += __shfl(a0, lane ^ 16); a1 += __shfl(a1, lane ^ 16);
    a2 += __shfl(a2, lane ^ 16); a3 += __shfl(a3, lane ^ 16);
    a4 += __shfl(a4, lane ^ 16); a5 += __shfl(a5, lane ^ 16);
    a6 += __shfl(a6, lane ^ 16); a7 += __shfl(a7, lane ^ 16);
    a0 += __shfl(a0, lane ^ 32); a1 += __shfl(a1, lane ^ 32);
    a2 += __shfl(a2, lane ^ 32); a3 += __shfl(a3, lane ^ 32);
    a4 += __shfl(a4, lane ^ 32); a5 += __shfl(a5, lane ^ 32);
    a6 += __shfl(a6, lane ^ 32); a7 += __shfl(a7, lane ^ 32);
    int d = end - beg;
    float inv = (d > 0) ? (1.f / (float)d) : 0.f;
    if (quad == 0) {
      uint4 o;
      o.x = (unsigned)f2bf(a0 * inv) | ((unsigned)f2bf(a1 * inv) << 16);
      o.y = (unsigned)f2bf(a2 * inv) | ((unsigned)f2bf(a3 * inv) << 16);
      o.z = (unsigned)f2bf(a4 * inv) | ((unsigned)f2bf(a5 * inv) << 16);
      o.w = (unsigned)f2bf(a6 * inv) | ((unsigned)f2bf(a7 * inv) << 16);
      out4[((unsigned)node << 4) + sl] = o;
    }
  }
}

// ============================ fused SAGE dual-GEMM via MFMA bf16 (R2-proven form) ===============
__global__ __launch_bounds__(256, 2)
void k_sage(const unsigned short* __restrict__ Am, const unsigned short* __restrict__ Ax,
            const unsigned short* __restrict__ WTl, const unsigned short* __restrict__ WTr,
            const float* __restrict__ bias, unsigned short* __restrict__ out, int n) {
  __shared__ unsigned short sA[128 * 64];
  __shared__ unsigned short sB[128 * 64];
  int tid = threadIdx.x;
  int lane = tid & 63;
  int w = tid >> 6;
  int row0 = blockIdx.x * 128;
  int col_lo = lane & 15, quad = lane >> 4;
  int rx = col_lo & 7;            // row&7 of every fragment row this lane reads

  f32x4 acc[2][8];
#pragma unroll
  for (int mt = 0; mt < 2; mt++)
#pragma unroll
    for (int nt = 0; nt < 8; nt++) acc[mt][nt] = (f32x4){0.f, 0.f, 0.f, 0.f};

  const unsigned short* As[4] = {Am, Am, Ax, Ax};
  const unsigned short* Bs[4] = {WTl, WTl, WTr, WTr};
  const int k0s[4] = {0, 64, 0, 64};

  for (int c = 0; c < 4; c++) {
    const unsigned short* Ap = As[c];
    const unsigned short* Bp = Bs[c];
    int k0 = k0s[c];
#pragma unroll
    for (int it = 0; it < 4; it++) {
      int flat = it * 256 + tid;
      int r = flat >> 3;
      int sl8 = flat & 7;
      int kof = (sl8 ^ (r & 7)) * 8;     // inverse-swizzled global slot
      int gr = row0 + r;
      if (gr > n - 1) gr = n - 1;
      gld16(Ap + (size_t)gr * CH + k0 + kof, sA + flat * 8);
      gld16(Bp + (size_t)r * CH + k0 + kof, sB + flat * 8);
    }
    __syncthreads();

#pragma unroll
    for (int ks = 0; ks < 2; ks++) {
      int so = ((ks * 4 + quad) ^ rx) * 8;   // swizzled slot offset (shorts)
      short8 a0 = *(const short8*)&sA[(w * 32 + col_lo) * 64 + so];
      short8 a1 = *(const short8*)&sA[(w * 32 + 16 + col_lo) * 64 + so];
      short8 b[8];
#pragma unroll
      for (int nt = 0; nt < 8; nt++)
        b[nt] = *(const short8*)&sB[(nt * 16 + col_lo) * 64 + so];
#pragma unroll
      for (int nt = 0; nt < 8; nt++) {
        acc[0][nt] = __builtin_amdgcn_mfma_f32_16x16x32_bf16(a0, b[nt], acc[0][nt], 0, 0, 0);
        acc[1][nt] = __builtin_amdgcn_mfma_f32_16x16x32_bf16(a1, b[nt], acc[1][nt], 0, 0, 0);
      }
    }
    __syncthreads();
  }

#pragma unroll
  for (int nt = 0; nt < 8; nt++) {
    float bb = bias[nt * 16 + col_lo];
#pragma unroll
    for (int mt = 0; mt < 2; mt++) {
#pragma unroll
      for (int r = 0; r < 4; r++) {
        int rr = row0 + w * 32 + mt * 16 + quad * 4 + r;
        if (rr < n) {
          float v = fmaxf(acc[mt][nt][r] + bb, 0.f);
          out[(size_t)rr * CH + nt * 16 + col_lo] = f2bf(v);
        }
      }
    }
  }
}

// ============================ decoder GEMM via MFMA (R2-proven form) ============================
__global__ __launch_bounds__(256, 2)
void k_dec(const unsigned short* __restrict__ H, const unsigned short* __restrict__ WTd,
           const float* __restrict__ bd, const float* __restrict__ X,
           const float* __restrict__ alpha_p, float* __restrict__ out, int n) {
  __shared__ unsigned short sA[128 * 64];
  __shared__ unsigned short sB[128 * 64];
  int tid = threadIdx.x;
  int lane = tid & 63;
  int w = tid >> 6;
  int row0 = blockIdx.x * 128;
  int col_lo = lane & 15, quad = lane >> 4;
  int rx = col_lo & 7;

  f32x4 acc[2][8];
#pragma unroll
  for (int mt = 0; mt < 2; mt++)
#pragma unroll
    for (int nt = 0; nt < 8; nt++) acc[mt][nt] = (f32x4){0.f, 0.f, 0.f, 0.f};

  for (int c = 0; c < 2; c++) {
    int k0 = c * 64;
#pragma unroll
    for (int it = 0; it < 4; it++) {
      int flat = it * 256 + tid;
      int r = flat >> 3;
      int sl8 = flat & 7;
      int kof = (sl8 ^ (r & 7)) * 8;
      int gr = row0 + r;
      if (gr > n - 1) gr = n - 1;
      gld16(H + (size_t)gr * CH + k0 + kof, sA + flat * 8);
      gld16(WTd + (size_t)r * CH + k0 + kof, sB + flat * 8);
    }
    __syncthreads();

#pragma unroll
    for (int ks = 0; ks < 2; ks++) {
      int so = ((ks * 4 + quad) ^ rx) * 8;
      short8 a0 = *(const short8*)&sA[(w * 32 + col_lo) * 64 + so];
      short8 a1 = *(const short8*)&sA[(w * 32 + 16 + col_lo) * 64 + so];
      short8 b[8];
#pragma unroll
      for (int nt = 0; nt < 8; nt++)
        b[nt] = *(const short8*)&sB[(nt * 16 + col_lo) * 64 + so];
#pragma unroll
      for (int nt = 0; nt < 8; nt++) {
        acc[0][nt] = __builtin_amdgcn_mfma_f32_16x16x32_bf16(a0, b[nt], acc[0][nt], 0, 0, 0);
        acc[1][nt] = __builtin_amdgcn_mfma_f32_16x16x32_bf16(a1, b[nt], acc[1][nt], 0, 0, 0);
      }
    }
    __syncthreads();
  }

  float al = alpha_p[0];
  float be = 1.f - al;
#pragma unroll
  for (int nt = 0; nt < 8; nt++) {
    float bb = bd[nt * 16 + col_lo];
#pragma unroll
    for (int mt = 0; mt < 2; mt++) {
#pragma unroll
      for (int r = 0; r < 4; r++) {
        int rr = row0 + w * 32 + mt * 16 + quad * 4 + r;
        if (rr < n) {
          int cc = nt * 16 + col_lo;
          float xv = X[(size_t)rr * CH + cc];
          out[(size_t)rr * CH + cc] = al * (acc[mt][nt][r] + bb) + be * xv;
        }
      }
    }
  }
}

// ============================ launch ============================

extern "C" void kernel_launch(void* const* d_in, const int* in_sizes, int n_in,
                              void* d_out, int out_size, void* d_ws, size_t ws_size,
                              hipStream_t stream) {
  const float* x   = (const float*)d_in[0];
  const int*   ei  = (const int*)d_in[1];
  const float* W1l = (const float*)d_in[2];
  const float* b1  = (const float*)d_in[3];
  const float* W1r = (const float*)d_in[4];
  const float* W2l = (const float*)d_in[5];
  const float* b2  = (const float*)d_in[6];
  const float* W2r = (const float*)d_in[7];
  const float* Wd  = (const float*)d_in[8];
  const float* bd  = (const float*)d_in[9];
  const float* alp = (const float*)d_in[10];

  int N = in_sizes[0] / CH;   // 100000
  int E = in_sizes[1] / 2;    // 1600000
  const int* src = ei;
  const int* dst = ei + E;

  char* ws = (char*)d_ws;
  size_t off = 0;
  auto alloc = [&](size_t bytes) -> char* {
    off = (off + 511) & ~size_t(511);
    char* p = ws + off;
    off += bytes;
    return p;
  };
  int*   rowptr = (int*)alloc((size_t)(N + 1) * 4);
  int*   cnt    = (int*)alloc((size_t)NBKT * 4);
  int*   sorted = (int*)alloc((size_t)E * 4);
  unsigned short* xb = (unsigned short*)alloc((size_t)N * CH * 2);
  unsigned short* h  = (unsigned short*)alloc((size_t)N * CH * 2);
  unsigned short* WT = (unsigned short*)alloc((size_t)5 * CH * CH * 2);
  unsigned short* mean = (unsigned short*)d_out;
  unsigned int* binned = (unsigned int*)((char*)d_out + (size_t)N * CH * 2);  // 8.03 MB fixed regions

  int chunk = (E + ABLK - 1) / ABLK;   // 5000
  int n8 = N * CH / 8;                 // 1,600,000
  int gCvt = (n8 + 1023) / 1024;       // 1563

  // 0) zero bucket counters (graph-capture-safe async memset)
  hipMemsetAsync(cnt, 0, (size_t)NBKT * 4, stream);
  // 1) fused binning + weight transpose + x convert (1024-thread blocks)
  k_prebin<<<ABLK + 5 + gCvt, 1024, 0, stream>>>(src, dst, cnt, binned, E, chunk,
                                                 (const float4*)x, (uint4*)xb, n8,
                                                 W1l, W1r, W2l, W2r, Wd, WT);
  // 2) bucket pass (1024-thread blocks)
  k_bucket<<<NBKT, 1024, 0, stream>>>(binned, cnt, rowptr, sorted, N, E, NBKT);

  int gAggBlocks = 6144;               // 24576 wave-slots, ~4 nodes/wave (3x oversubscribed)
  int nWaves = gAggBlocks * 4;
  int gGemm = (N + 127) / 128;
  unsigned short* WT1l = WT + 0 * CH * CH;
  unsigned short* WT1r = WT + 1 * CH * CH;
  unsigned short* WT2l = WT + 2 * CH * CH;
  unsigned short* WT2r = WT + 3 * CH * CH;
  unsigned short* WTd  = WT + 4 * CH * CH;

  k_agg<<<gAggBlocks, 256, 0, stream>>>((const uint4*)xb, (uint4*)mean, rowptr, sorted, N, nWaves);
  k_sage<<<gGemm, 256, 0, stream>>>(mean, xb, WT1l, WT1r, b1, h, N);
  k_agg<<<gAggBlocks, 256, 0, stream>>>((const uint4*)h, (uint4*)mean, rowptr, sorted, N, nWaves);
  k_sage<<<gGemm, 256, 0, stream>>>(mean, h, WT2l, WT2r, b2, h, N);
  k_dec<<<gGemm, 256, 0, stream>>>(h, WTd, bd, x, alp, (float*)d_out, N);
}